// Round 2
// baseline (325.109 us; speedup 1.0000x reference)
//
#include <hip/hip_runtime.h>
#include <cstdint>
#include <cstddef>

#define B_    32
#define S_    2048
#define D_    64
#define QBLK  16            // q rows per block
#define SP    2056          // padded P_lds row stride (shorts): 2048 + 8

typedef __attribute__((ext_vector_type(8))) short short8_t;  // 8 bf16 (4 VGPRs)
typedef __attribute__((ext_vector_type(4))) float f32x4;     // MFMA acc

__device__ __forceinline__ short f2bf(float f) {
  union { float f; unsigned u; } x; x.f = f;
  unsigned u = x.u;
  u += 0x7fffu + ((u >> 16) & 1u);   // round-to-nearest-even
  return (short)(u >> 16);
}

// ---- fp32 -> bf16 elementwise (for K) ----
__global__ void convert_bf16_kernel(const float* __restrict__ in,
                                    short* __restrict__ out, int n4) {
  int i = blockIdx.x * blockDim.x + threadIdx.x;
  if (i >= n4) return;
  f32x4 f = ((const f32x4*)in)[i];
  short4 o;
  o.x = f2bf(f[0]); o.y = f2bf(f[1]); o.z = f2bf(f[2]); o.w = f2bf(f[3]);
  ((short4*)out)[i] = o;
}

// ---- V [B][S][D] fp32 -> Vt [B][D][S] bf16 (so PV B-frags are contiguous) ----
__global__ void transpose_v_kernel(const float* __restrict__ v,
                                   short* __restrict__ vt) {
  __shared__ float t[64][65];                 // +1 pad: conflict-free col reads
  int b   = blockIdx.x >> 5;                  // S_/64 = 32 tiles per batch
  int st  = blockIdx.x & 31;
  int tid = threadIdx.x;
  const float* src = v + ((size_t)(b * S_ + st * 64)) * D_;
#pragma unroll
  for (int p = 0; p < 4; ++p) {
    int r = p * 16 + (tid >> 4);
    int c = (tid & 15) * 4;
    f32x4 f = *(const f32x4*)(src + (size_t)r * D_ + c);
    t[r][c] = f[0]; t[r][c+1] = f[1]; t[r][c+2] = f[2]; t[r][c+3] = f[3];
  }
  __syncthreads();
#pragma unroll
  for (int p = 0; p < 8; ++p) {
    int d  = p * 8 + (tid >> 5);
    int si = (tid & 31) * 2;
    unsigned lo = (unsigned short)f2bf(t[si][d]);
    unsigned hi = (unsigned short)f2bf(t[si + 1][d]);
    *(unsigned*)(vt + ((size_t)(b * D_ + d)) * S_ + st * 64 + si) = lo | (hi << 16);
  }
}

// ==== main fused kernel ====
// Per block: 16 q-rows, full S_k, 8 waves (each wave owns a 256-col k slice).
// Swapped QK^T: acc = mfma(Kfrag, Qfrag) -> S^T layout:
//   lane (lq,lr) holds S[q = qbase+lr][k = wcol + ct*16 + lq*4 + i], i=0..3
// -> per-lane softmax (64 regs local + shfl_xor 16/32), float4 attn stores,
//    8B P_lds writes. 2 blocks/CU resident (LDS ~69.5 KB) for phase overlap.
template <bool WS>
__global__ __launch_bounds__(512, 4)
void attn_kernel(const float* __restrict__ q, const float* __restrict__ k,
                 const float* __restrict__ v, const short* __restrict__ Kb,
                 const short* __restrict__ Vt, float* __restrict__ out,
                 float* __restrict__ attn) {
  __shared__ short P_lds[QBLK][SP];          // 65792 B
  __shared__ float redmax[QBLK][8];          // 512 B
  __shared__ float redsum[QBLK][8];          // 512 B
  __shared__ float Ored[4][16][17];          // 4352 B (pad 17: no bank conflict)

  const int tid  = threadIdx.x;
  const int lane = tid & 63;
  const int wv   = tid >> 6;     // 0..7
  const int lr   = lane & 15;
  const int lq   = lane >> 4;    // 0..3

  // XCD-aware bijective swizzle (gridDim.x = 4096, %8 == 0)
  const int nwg  = gridDim.x;
  const int per  = nwg >> 3;
  const int bid0 = blockIdx.x;
  const int bid  = (bid0 & 7) * per + (bid0 >> 3);

  const int b     = bid >> 7;            // 128 q-tiles per batch
  const int qbase = (bid & 127) * QBLK;

  // ---------- load Q fragment (B-operand): lane holds Q[qbase+lr][lq*8+e] ----------
  short8_t qf[2];
  {
    const float* qp = q + ((size_t)(b * S_ + qbase + lr)) * D_ + lq * 8;
#pragma unroll
    for (int kp = 0; kp < 2; ++kp) {
      f32x4 f0 = *(const f32x4*)(qp + kp * 32);
      f32x4 f1 = *(const f32x4*)(qp + kp * 32 + 4);
      short8_t a;
      a[0] = f2bf(f0[0]); a[1] = f2bf(f0[1]); a[2] = f2bf(f0[2]); a[3] = f2bf(f0[3]);
      a[4] = f2bf(f1[0]); a[5] = f2bf(f1[1]); a[6] = f2bf(f1[2]); a[7] = f2bf(f1[3]);
      qf[kp] = a;
    }
  }

  // ---------- Phase 1: S^T = K Q^T ----------
  f32x4 acc[16];
#pragma unroll
  for (int ct = 0; ct < 16; ++ct) acc[ct] = (f32x4){0.f, 0.f, 0.f, 0.f};

  const int wcol = wv * 256;
#pragma unroll
  for (int ct = 0; ct < 16; ++ct) {
    int n = wcol + ct * 16 + lr;           // key row
    short8_t b0, b1;
    if constexpr (WS) {
      const short* kr = Kb + ((size_t)(b * S_ + n)) * D_ + lq * 8;
      b0 = *(const short8_t*)(kr);
      b1 = *(const short8_t*)(kr + 32);
    } else {
      const float* kr = k + ((size_t)(b * S_ + n)) * D_ + lq * 8;
      f32x4 f0 = *(const f32x4*)(kr);
      f32x4 f1 = *(const f32x4*)(kr + 4);
      f32x4 f2 = *(const f32x4*)(kr + 32);
      f32x4 f3 = *(const f32x4*)(kr + 36);
      b0[0]=f2bf(f0[0]); b0[1]=f2bf(f0[1]); b0[2]=f2bf(f0[2]); b0[3]=f2bf(f0[3]);
      b0[4]=f2bf(f1[0]); b0[5]=f2bf(f1[1]); b0[6]=f2bf(f1[2]); b0[7]=f2bf(f1[3]);
      b1[0]=f2bf(f2[0]); b1[1]=f2bf(f2[1]); b1[2]=f2bf(f2[2]); b1[3]=f2bf(f2[3]);
      b1[4]=f2bf(f3[0]); b1[5]=f2bf(f3[1]); b1[6]=f2bf(f3[2]); b1[7]=f2bf(f3[3]);
    }
    // swapped operands: A = K rows, B = Q rows  ->  D[k][q]
    acc[ct] = __builtin_amdgcn_mfma_f32_16x16x32_bf16(b0, qf[0], acc[ct], 0, 0, 0);
    acc[ct] = __builtin_amdgcn_mfma_f32_16x16x32_bf16(b1, qf[1], acc[ct], 0, 0, 0);
  }

  // ---------- Phase 2: softmax (per-lane row-local) ----------
  float m = acc[0][0];
#pragma unroll
  for (int ct = 0; ct < 16; ++ct)
#pragma unroll
    for (int i = 0; i < 4; ++i) m = fmaxf(m, acc[ct][i]);
  m = fmaxf(m, __shfl_xor(m, 16));
  m = fmaxf(m, __shfl_xor(m, 32));
  if (lane < 16) redmax[lr][wv] = m;
  __syncthreads();
  float mf = redmax[lr][0];
#pragma unroll
  for (int w2 = 1; w2 < 8; ++w2) mf = fmaxf(mf, redmax[lr][w2]);

  float s = 0.f;
#pragma unroll
  for (int ct = 0; ct < 16; ++ct)
#pragma unroll
    for (int i = 0; i < 4; ++i) {
      float p = __expf((acc[ct][i] - mf) * 0.125f);   // / TEMPERATURE
      acc[ct][i] = p;
      s += p;
    }
  s += __shfl_xor(s, 16);
  s += __shfl_xor(s, 32);
  if (lane < 16) redsum[lr][wv] = s;
  __syncthreads();
  float sum = 0.f;
#pragma unroll
  for (int w2 = 0; w2 < 8; ++w2) sum += redsum[lr][w2];
  const float rl = 1.f / sum;

  // ---------- Phase 3: write attn (float4 NT) + P_lds (8B bf16 packs) ----------
  float* ap = attn + ((size_t)b * S_ + qbase + lr) * S_ + wcol;
#pragma unroll
  for (int ct = 0; ct < 16; ++ct) {
    f32x4 av;
    av[0] = acc[ct][0] * rl; av[1] = acc[ct][1] * rl;
    av[2] = acc[ct][2] * rl; av[3] = acc[ct][3] * rl;
    __builtin_nontemporal_store(av, (f32x4*)(ap + ct * 16 + lq * 4));
    unsigned lo = (unsigned)(unsigned short)f2bf(av[0]) |
                  ((unsigned)(unsigned short)f2bf(av[1]) << 16);
    unsigned hi = (unsigned)(unsigned short)f2bf(av[2]) |
                  ((unsigned)(unsigned short)f2bf(av[3]) << 16);
    uint2 pk; pk.x = lo; pk.y = hi;
    *(uint2*)&P_lds[lr][wcol + ct * 16 + lq * 4] = pk;
  }
  __syncthreads();

  // ---------- Phase 4: O = P @ V ----------
  const int cc = wv & 3;       // d-tile
  const int hh = wv >> 2;      // k-half
  const int dbase = cc * 16;
  f32x4 oacc = (f32x4){0.f, 0.f, 0.f, 0.f};
  const short* vrow = WS ? (Vt + ((size_t)(b * D_ + dbase + lr)) * S_ + hh * 1024)
                         : nullptr;
#pragma unroll 4
  for (int st2 = 0; st2 < 32; ++st2) {
    int kidx = st2 * 32 + lq * 8;
    short8_t p0 = *(const short8_t*)&P_lds[lr][hh * 1024 + kidx];
    short8_t vb;
    if constexpr (WS) {
      vb = *(const short8_t*)(vrow + kidx);
    } else {
#pragma unroll
      for (int e = 0; e < 8; ++e)
        vb[e] = f2bf(v[((size_t)(b * S_ + hh * 1024 + kidx + e)) * D_ + dbase + lr]);
    }
    oacc = __builtin_amdgcn_mfma_f32_16x16x32_bf16(p0, vb, oacc, 0, 0, 0);
  }
  if (hh == 1) {
#pragma unroll
    for (int i = 0; i < 4; ++i)
      Ored[cc][lq * 4 + i][lr] = oacc[i];
  }
  __syncthreads();
  if (hh == 0) {
#pragma unroll
    for (int i = 0; i < 4; ++i) {
      float o = oacc[i] + Ored[cc][lq * 4 + i][lr];
      out[((size_t)(b * S_ + qbase + lq * 4 + i)) * D_ + dbase + lr] = o;
    }
  }
}

extern "C" void kernel_launch(void* const* d_in, const int* in_sizes, int n_in,
                              void* d_out, int out_size, void* d_ws, size_t ws_size,
                              hipStream_t stream) {
  (void)in_sizes; (void)n_in; (void)out_size;
  const float* q = (const float*)d_in[0];
  const float* k = (const float*)d_in[1];
  const float* v = (const float*)d_in[2];
  float* out  = (float*)d_out;
  float* attn = out + (size_t)B_ * S_ * D_;

  const size_t nelem = (size_t)B_ * S_ * D_;        // 4,194,304
  const size_t need  = nelem * 2 * sizeof(short);   // Kb + Vt = 16 MB

  dim3 grid(B_ * (S_ / QBLK));                      // 4096 blocks
  if (d_ws != nullptr && ws_size >= need) {
    short* Kb = (short*)d_ws;
    short* Vt = Kb + nelem;
    convert_bf16_kernel<<<(int)((nelem / 4 + 255) / 256), 256, 0, stream>>>(k, Kb, (int)(nelem / 4));
    transpose_v_kernel<<<B_ * (S_ / 64), 256, 0, stream>>>(v, Vt);
    attn_kernel<true><<<grid, 512, 0, stream>>>(q, k, v, Kb, Vt, out, attn);
  } else {
    attn_kernel<false><<<grid, 512, 0, stream>>>(q, k, v, nullptr, nullptr, out, attn);
  }
}

// Round 3
// 280.231 us; speedup vs baseline: 1.1601x; 1.1601x over previous
//
#include <hip/hip_runtime.h>
#include <cstdint>
#include <cstddef>

#define B_    32
#define S_    2048
#define D_    64
#define QBLK  16            // q rows per block
#define SP    2056          // padded P_lds row stride (shorts): 2048 + 8

typedef __attribute__((ext_vector_type(8))) short short8_t;  // 8 bf16 (4 VGPRs)
typedef __attribute__((ext_vector_type(4))) float f32x4;     // MFMA acc

__device__ __forceinline__ short f2bf(float f) {
  union { float f; unsigned u; } x; x.f = f;
  unsigned u = x.u;
  u += 0x7fffu + ((u >> 16) & 1u);   // round-to-nearest-even
  return (short)(u >> 16);
}
__device__ __forceinline__ float bf2f(unsigned s) {
  union { unsigned u; float f; } x;
  x.u = (s & 0xffffu) << 16;
  return x.f;
}

// ---- fp32 -> bf16 elementwise (for K) ----
__global__ void convert_bf16_kernel(const float* __restrict__ in,
                                    short* __restrict__ out, int n4) {
  int i = blockIdx.x * blockDim.x + threadIdx.x;
  if (i >= n4) return;
  f32x4 f = ((const f32x4*)in)[i];
  short4 o;
  o.x = f2bf(f[0]); o.y = f2bf(f[1]); o.z = f2bf(f[2]); o.w = f2bf(f[3]);
  ((short4*)out)[i] = o;
}

// ---- V [B][S][D] fp32 -> Vt [B][D][S] bf16 (so PV B-frags are contiguous) ----
__global__ void transpose_v_kernel(const float* __restrict__ v,
                                   short* __restrict__ vt) {
  __shared__ float t[64][65];                 // +1 pad: conflict-free col reads
  int b   = blockIdx.x >> 5;                  // S_/64 = 32 tiles per batch
  int st  = blockIdx.x & 31;
  int tid = threadIdx.x;
  const float* src = v + ((size_t)(b * S_ + st * 64)) * D_;
#pragma unroll
  for (int p = 0; p < 4; ++p) {
    int r = p * 16 + (tid >> 4);
    int c = (tid & 15) * 4;
    f32x4 f = *(const f32x4*)(src + (size_t)r * D_ + c);
    t[r][c] = f[0]; t[r][c+1] = f[1]; t[r][c+2] = f[2]; t[r][c+3] = f[3];
  }
  __syncthreads();
#pragma unroll
  for (int p = 0; p < 8; ++p) {
    int d  = p * 8 + (tid >> 5);
    int si = (tid & 31) * 2;
    unsigned lo = (unsigned short)f2bf(t[si][d]);
    unsigned hi = (unsigned short)f2bf(t[si + 1][d]);
    *(unsigned*)(vt + ((size_t)(b * D_ + d)) * S_ + st * 64 + si) = lo | (hi << 16);
  }
}

// ==== main fused kernel ====
// Per block: 16 q-rows, full S_k, 8 waves (each wave owns a 256-col k slice).
// Swapped QK^T -> S^T reg layout; softmax per-lane; P staged bf16 in LDS.
// attn is then streamed from LDS with DENSE 1KB-per-instruction float4 stores
// (each wave owns 2 whole rows) — this is the write-BW-critical path.
template <bool WS>
__global__ __launch_bounds__(512, 4)
void attn_kernel(const float* __restrict__ q, const float* __restrict__ k,
                 const float* __restrict__ v, const short* __restrict__ Kb,
                 const short* __restrict__ Vt, float* __restrict__ out,
                 float* __restrict__ attn) {
  __shared__ short P_lds[QBLK][SP];          // 65792 B
  __shared__ float redmax[QBLK][8];          // 512 B
  __shared__ float redsum[QBLK][8];          // 512 B
  __shared__ float Ored[4][16][17];          // 4352 B (pad 17: no bank conflict)

  const int tid  = threadIdx.x;
  const int lane = tid & 63;
  const int wv   = tid >> 6;     // 0..7
  const int lr   = lane & 15;
  const int lq   = lane >> 4;    // 0..3

  // XCD-aware bijective swizzle (gridDim.x = 4096, %8 == 0)
  const int nwg  = gridDim.x;
  const int per  = nwg >> 3;
  const int bid0 = blockIdx.x;
  const int bid  = (bid0 & 7) * per + (bid0 >> 3);

  const int b     = bid >> 7;            // 128 q-tiles per batch
  const int qbase = (bid & 127) * QBLK;

  // ---------- load Q fragment (B-operand): lane holds Q[qbase+lr][lq*8+e] ----------
  short8_t qf[2];
  {
    const float* qp = q + ((size_t)(b * S_ + qbase + lr)) * D_ + lq * 8;
#pragma unroll
    for (int kp = 0; kp < 2; ++kp) {
      f32x4 f0 = *(const f32x4*)(qp + kp * 32);
      f32x4 f1 = *(const f32x4*)(qp + kp * 32 + 4);
      short8_t a;
      a[0] = f2bf(f0[0]); a[1] = f2bf(f0[1]); a[2] = f2bf(f0[2]); a[3] = f2bf(f0[3]);
      a[4] = f2bf(f1[0]); a[5] = f2bf(f1[1]); a[6] = f2bf(f1[2]); a[7] = f2bf(f1[3]);
      qf[kp] = a;
    }
  }

  // ---------- Phase 1: S^T = K Q^T ----------
  f32x4 acc[16];
#pragma unroll
  for (int ct = 0; ct < 16; ++ct) acc[ct] = (f32x4){0.f, 0.f, 0.f, 0.f};

  const int wcol = wv * 256;
#pragma unroll
  for (int ct = 0; ct < 16; ++ct) {
    int n = wcol + ct * 16 + lr;           // key row
    short8_t b0, b1;
    if constexpr (WS) {
      const short* kr = Kb + ((size_t)(b * S_ + n)) * D_ + lq * 8;
      b0 = *(const short8_t*)(kr);
      b1 = *(const short8_t*)(kr + 32);
    } else {
      const float* kr = k + ((size_t)(b * S_ + n)) * D_ + lq * 8;
      f32x4 f0 = *(const f32x4*)(kr);
      f32x4 f1 = *(const f32x4*)(kr + 4);
      f32x4 f2 = *(const f32x4*)(kr + 32);
      f32x4 f3 = *(const f32x4*)(kr + 36);
      b0[0]=f2bf(f0[0]); b0[1]=f2bf(f0[1]); b0[2]=f2bf(f0[2]); b0[3]=f2bf(f0[3]);
      b0[4]=f2bf(f1[0]); b0[5]=f2bf(f1[1]); b0[6]=f2bf(f1[2]); b0[7]=f2bf(f1[3]);
      b1[0]=f2bf(f2[0]); b1[1]=f2bf(f2[1]); b1[2]=f2bf(f2[2]); b1[3]=f2bf(f2[3]);
      b1[4]=f2bf(f3[0]); b1[5]=f2bf(f3[1]); b1[6]=f2bf(f3[2]); b1[7]=f2bf(f3[3]);
    }
    // swapped operands: A = K rows, B = Q rows  ->  D[k][q]
    acc[ct] = __builtin_amdgcn_mfma_f32_16x16x32_bf16(b0, qf[0], acc[ct], 0, 0, 0);
    acc[ct] = __builtin_amdgcn_mfma_f32_16x16x32_bf16(b1, qf[1], acc[ct], 0, 0, 0);
  }

  // ---------- Phase 2: softmax (per-lane row-local) ----------
  float m = acc[0][0];
#pragma unroll
  for (int ct = 0; ct < 16; ++ct)
#pragma unroll
    for (int i = 0; i < 4; ++i) m = fmaxf(m, acc[ct][i]);
  m = fmaxf(m, __shfl_xor(m, 16));
  m = fmaxf(m, __shfl_xor(m, 32));
  if (lane < 16) redmax[lr][wv] = m;
  __syncthreads();
  float mf = redmax[lr][0];
#pragma unroll
  for (int w2 = 1; w2 < 8; ++w2) mf = fmaxf(mf, redmax[lr][w2]);

  float s = 0.f;
#pragma unroll
  for (int ct = 0; ct < 16; ++ct)
#pragma unroll
    for (int i = 0; i < 4; ++i) {
      float p = __expf((acc[ct][i] - mf) * 0.125f);   // / TEMPERATURE
      acc[ct][i] = p;
      s += p;
    }
  s += __shfl_xor(s, 16);
  s += __shfl_xor(s, 32);
  if (lane < 16) redsum[lr][wv] = s;
  __syncthreads();
  float sum = 0.f;
#pragma unroll
  for (int w2 = 0; w2 < 8; ++w2) sum += redsum[lr][w2];
  const float rl = 1.f / sum;

  // ---------- Phase 3a: stage normalized P into LDS (bf16) ----------
#pragma unroll
  for (int ct = 0; ct < 16; ++ct) {
    unsigned lo = (unsigned)(unsigned short)f2bf(acc[ct][0] * rl) |
                  ((unsigned)(unsigned short)f2bf(acc[ct][1] * rl) << 16);
    unsigned hi = (unsigned)(unsigned short)f2bf(acc[ct][2] * rl) |
                  ((unsigned)(unsigned short)f2bf(acc[ct][3] * rl) << 16);
    uint2 pk; pk.x = lo; pk.y = hi;
    *(uint2*)&P_lds[lr][wcol + ct * 16 + lq * 4] = pk;
  }
  __syncthreads();

  // ---------- Phase 3b: stream attn rows, DENSE 1KB/instr float4 stores ----------
  {
    const int r0 = wv * 2;                      // each wave owns 2 whole rows
#pragma unroll
    for (int rr = 0; rr < 2; ++rr) {
      const int r = r0 + rr;
      float* arow = attn + ((size_t)b * S_ + qbase + r) * S_;
#pragma unroll
      for (int it = 0; it < 8; ++it) {
        const int col = it * 256 + lane * 4;
        uint2 pk = *(const uint2*)&P_lds[r][col];
        f32x4 o;
        o[0] = bf2f(pk.x);
        o[1] = bf2f(pk.x >> 16);
        o[2] = bf2f(pk.y);
        o[3] = bf2f(pk.y >> 16);
        __builtin_nontemporal_store(o, (f32x4*)(arow + col));
      }
    }
  }

  // ---------- Phase 4: O = P @ V ----------
  const int cc = wv & 3;       // d-tile
  const int hh = wv >> 2;      // k-half
  const int dbase = cc * 16;
  f32x4 oacc = (f32x4){0.f, 0.f, 0.f, 0.f};
  const short* vrow = WS ? (Vt + ((size_t)(b * D_ + dbase + lr)) * S_ + hh * 1024)
                         : nullptr;
#pragma unroll 4
  for (int st2 = 0; st2 < 32; ++st2) {
    int kidx = st2 * 32 + lq * 8;
    short8_t p0 = *(const short8_t*)&P_lds[lr][hh * 1024 + kidx];
    short8_t vb;
    if constexpr (WS) {
      vb = *(const short8_t*)(vrow + kidx);
    } else {
#pragma unroll
      for (int e = 0; e < 8; ++e)
        vb[e] = f2bf((unsigned)(unsigned short)f2bf(0) + 0), vb[e] = f2bf(v[((size_t)(b * S_ + hh * 1024 + kidx + e)) * D_ + dbase + lr]);
    }
    oacc = __builtin_amdgcn_mfma_f32_16x16x32_bf16(p0, vb, oacc, 0, 0, 0);
  }
  if (hh == 1) {
#pragma unroll
    for (int i = 0; i < 4; ++i)
      Ored[cc][lq * 4 + i][lr] = oacc[i];
  }
  __syncthreads();
  if (hh == 0) {
#pragma unroll
    for (int i = 0; i < 4; ++i) {
      float o = oacc[i] + Ored[cc][lq * 4 + i][lr];
      out[((size_t)(b * S_ + qbase + lq * 4 + i)) * D_ + dbase + lr] = o;
    }
  }
}

extern "C" void kernel_launch(void* const* d_in, const int* in_sizes, int n_in,
                              void* d_out, int out_size, void* d_ws, size_t ws_size,
                              hipStream_t stream) {
  (void)in_sizes; (void)n_in; (void)out_size;
  const float* q = (const float*)d_in[0];
  const float* k = (const float*)d_in[1];
  const float* v = (const float*)d_in[2];
  float* out  = (float*)d_out;
  float* attn = out + (size_t)B_ * S_ * D_;

  const size_t nelem = (size_t)B_ * S_ * D_;        // 4,194,304
  const size_t need  = nelem * 2 * sizeof(short);   // Kb + Vt = 16 MB

  dim3 grid(B_ * (S_ / QBLK));                      // 4096 blocks
  if (d_ws != nullptr && ws_size >= need) {
    short* Kb = (short*)d_ws;
    short* Vt = Kb + nelem;
    convert_bf16_kernel<<<(int)((nelem / 4 + 255) / 256), 256, 0, stream>>>(k, Kb, (int)(nelem / 4));
    transpose_v_kernel<<<B_ * (S_ / 64), 256, 0, stream>>>(v, Vt);
    attn_kernel<true><<<grid, 512, 0, stream>>>(q, k, v, Kb, Vt, out, attn);
  } else {
    attn_kernel<false><<<grid, 512, 0, stream>>>(q, k, v, nullptr, nullptr, out, attn);
  }
}